// Round 3
// baseline (318.837 us; speedup 1.0000x reference)
//
#include <hip/hip_runtime.h>

// out[b,c,l,m] = sum_{s,t} xp[b,c,l+s] * F[c,s,t] * xp[b,c,m+t]
// Decomposition: xf[bc,t,l] = sum_s xp[l+s] * F[c,s,t]  (materialized in d_ws, 2.2 MB, t-major)
//                out[bc,l,m] = sum_t xf[bc,t,l] * xp[m+t]
// x: [8,2,2048] f32, filt: [1,2,17,17] f32, out: [8,2,2048,2048] f32 (268 MB)
// HBM-write-bound: floor ~ 268MB / ~6.3 TB/s ~ 43 us for the out kernel.
//
// v2 (2nd resubmit after infra failures): out kernel re-tiled 64x64 -> 32x256
//     (4x8 register tile / thread).
//     - 1 KB contiguous row chunks per block (was 256 B) -> better DRAM write locality
//     - w-window loaded as 6x ds_read_b128 (was 20x ds_read_b32)
//     - ds_read_b128 fragment reads amortized over 8 m-cols (was 4)
//     Accumulation order over t unchanged -> bit-identical output.

#define LN   2048
#define S    17
#define PADW 8
#define NBC  16

// out-kernel tile
#define QTL  32
#define QTM  256

typedef float f32x4 __attribute__((ext_vector_type(4)));

// ---------------- kernel 1: xf[bc][t][l] = sum_s xp[bc][l+s] * F[c][s][t] -------------
__global__ __launch_bounds__(256) void xf_kernel(
    const float* __restrict__ x,
    const float* __restrict__ filt,
    float* __restrict__ xf)   // [NBC][S][LN]
{
    const int bc = blockIdx.y;
    const int c  = bc & 1;
    const int l  = blockIdx.x * 256 + threadIdx.x;

    __shared__ float sF[S][S];
    for (int i = threadIdx.x; i < S * S; i += 256)
        sF[i / S][i % S] = filt[c * S * S + i];
    __syncthreads();

    const float* __restrict__ xrow = x + (size_t)bc * LN;

    // window xp[l .. l+16] (xp pad 8 each side)
    float w[S];
#pragma unroll
    for (int s = 0; s < S; s++) {
        int j = l + s - PADW;
        w[s] = (j >= 0 && j < LN) ? xrow[j] : 0.0f;
    }

    float acc[S];
#pragma unroll
    for (int t = 0; t < S; t++) acc[t] = 0.0f;
#pragma unroll
    for (int s = 0; s < S; s++) {
        const float ws = w[s];
#pragma unroll
        for (int t = 0; t < S; t++)
            acc[t] += ws * sF[s][t];
    }

    float* __restrict__ xfrow = xf + (size_t)bc * S * LN + l;
#pragma unroll
    for (int t = 0; t < S; t++)
        xfrow[(size_t)t * LN] = acc[t];
}

// ---------------- kernel 2: out tile 32(l) x 256(m), store-bound ----------------
__global__ __launch_bounds__(256) void filter_qf_kernel(
    const float* __restrict__ x,
    const float* __restrict__ xf,   // [NBC][S][LN]
    float* __restrict__ out)
{
    const int bc = blockIdx.z;
    const int l0 = blockIdx.y * QTL;
    const int m0 = blockIdx.x * QTM;
    const int tid = threadIdx.x;

    __shared__ __align__(16) float sxf[S][QTL];         // 17*32*4 = 2176 B, t-major
    __shared__ __align__(16) float sxm[QTM + S - 1];    // 272*4 = 1088 B

    // stage xf tile: 17*32 = 544 floats, coalesced (L2/L3-resident source)
    const float* __restrict__ xfbase = xf + (size_t)bc * S * LN + l0;
    for (int i = tid; i < S * QTL; i += 256) {
        int t = i >> 5, l = i & 31;
        sxf[t][l] = xfbase[(size_t)t * LN + l];
    }
    // stage m-window (272 floats, with zero-pad semantics)
    const float* __restrict__ xrow = x + (size_t)bc * LN;
    for (int i = tid; i < QTM + S - 1; i += 256) {
        int j = m0 + i - PADW;
        sxm[i] = (j >= 0 && j < LN) ? xrow[j] : 0.0f;
    }
    __syncthreads();

    // 32 (m) x 8 (l) thread grid; 4l x 8m register tile each
    const int tm = (tid & 31) << 3;   // 0..248, 32B-aligned in LDS
    const int tl = (tid >> 5) << 2;   // 0..28

    // w = sxm[tm .. tm+24): 6 x ds_read_b128 (16B-aligned: tm multiple of 8 floats)
    float w[24];
#pragma unroll
    for (int k = 0; k < 6; k++)
        *reinterpret_cast<f32x4*>(&w[4 * k]) =
            *reinterpret_cast<const f32x4*>(&sxm[tm + 4 * k]);

    float acc[4][8] = {};
#pragma unroll
    for (int t = 0; t < S; t++) {
        // one broadcast ds_read_b128 per t (all 32 lanes of an l-group share the address)
        const f32x4 f = *reinterpret_cast<const f32x4*>(&sxf[t][tl]);
#pragma unroll
        for (int j = 0; j < 8; j++) {
            const float b = w[t + j];
#pragma unroll
            for (int i = 0; i < 4; i++)
                acc[i][j] += f[i] * b;
        }
    }

    // stores: per row, 32 threads x 32B = 1 KB contiguous
    size_t base = (((size_t)bc * LN) + (size_t)(l0 + tl)) * LN + (size_t)(m0 + tm);
#pragma unroll
    for (int li = 0; li < 4; li++) {
        f32x4 v0 = { acc[li][0], acc[li][1], acc[li][2], acc[li][3] };
        f32x4 v1 = { acc[li][4], acc[li][5], acc[li][6], acc[li][7] };
        float* p = out + base + (size_t)li * LN;
        __builtin_nontemporal_store(v0, reinterpret_cast<f32x4*>(p));
        __builtin_nontemporal_store(v1, reinterpret_cast<f32x4*>(p + 4));
    }
}

// ---------------- fallback (round-1 kernel, 64x64 tile) if ws too small ----------------
#define FTL  64
#define FTM  64

__global__ __launch_bounds__(256) void filter_qf_fallback(
    const float* __restrict__ x,
    const float* __restrict__ filt,
    float* __restrict__ out)
{
    const int bc = blockIdx.z;
    const int c  = bc & 1;
    const int l0 = blockIdx.y * FTL;
    const int m0 = blockIdx.x * FTM;
    const int tid = threadIdx.x;

    __shared__ float sF[S][S];
    __shared__ float sxl[FTL + S - 1];
    __shared__ float sxm[FTM + S - 1];
    __shared__ float sxf[FTL][S + 1];

    const float* __restrict__ xrow = x + (size_t)bc * LN;
    for (int i = tid; i < S * S; i += 256)
        sF[i / S][i % S] = filt[c * S * S + i];
    for (int i = tid; i < FTL + S - 1; i += 256) {
        int j = l0 + i - PADW;
        sxl[i] = (j >= 0 && j < LN) ? xrow[j] : 0.0f;
    }
    for (int i = tid; i < FTM + S - 1; i += 256) {
        int j = m0 + i - PADW;
        sxm[i] = (j >= 0 && j < LN) ? xrow[j] : 0.0f;
    }
    __syncthreads();
    for (int i = tid; i < FTL * S; i += 256) {
        int l = i / S, t = i % S;
        float a = 0.0f;
#pragma unroll
        for (int s = 0; s < S; s++) a += sxl[l + s] * sF[s][t];
        sxf[l][t] = a;
    }
    __syncthreads();
    const int tm = (tid & 15) << 2;
    const int tl = (tid >> 4) << 2;
    float w[4 + S - 1];
#pragma unroll
    for (int i = 0; i < 4 + S - 1; i++) w[i] = sxm[tm + i];
    float acc[4][4] = {{0.f}};
#pragma unroll
    for (int t = 0; t < S; t++) {
        const float f0 = sxf[tl + 0][t], f1 = sxf[tl + 1][t];
        const float f2 = sxf[tl + 2][t], f3 = sxf[tl + 3][t];
#pragma unroll
        for (int j = 0; j < 4; j++) {
            const float b = w[t + j];
            acc[0][j] += f0 * b; acc[1][j] += f1 * b;
            acc[2][j] += f2 * b; acc[3][j] += f3 * b;
        }
    }
    size_t base = (((size_t)bc * LN) + (size_t)(l0 + tl)) * LN + (size_t)(m0 + tm);
#pragma unroll
    for (int li = 0; li < 4; li++) {
        f32x4 v = { acc[li][0], acc[li][1], acc[li][2], acc[li][3] };
        *reinterpret_cast<f32x4*>(out + base + (size_t)li * LN) = v;
    }
}

extern "C" void kernel_launch(void* const* d_in, const int* in_sizes, int n_in,
                              void* d_out, int out_size, void* d_ws, size_t ws_size,
                              hipStream_t stream) {
    const float* x    = (const float*)d_in[0];   // [8,2,2048]
    const float* filt = (const float*)d_in[1];   // [1,2,17,17]
    float* out = (float*)d_out;                  // [8,2,2048,2048]

    const size_t xf_bytes = (size_t)NBC * S * LN * sizeof(float);  // 2.2 MB

    if (ws_size >= xf_bytes) {
        float* xf = (float*)d_ws;
        xf_kernel<<<dim3(LN / 256, NBC), 256, 0, stream>>>(x, filt, xf);
        filter_qf_kernel<<<dim3(LN / QTM, LN / QTL, NBC), 256, 0, stream>>>(x, xf, out);
    } else {
        filter_qf_fallback<<<dim3(LN / FTM, LN / FTL, NBC), 256, 0, stream>>>(x, filt, out);
    }
}

// Round 4
// 276.394 us; speedup vs baseline: 1.1536x; 1.1536x over previous
//
#include <hip/hip_runtime.h>

// out[b,c,l,m] = sum_{s,t} xp[b,c,l+s] * F[c,s,t] * xp[b,c,m+t]
// Decomposition: xf[bc,t,l] = sum_s xp[l+s] * F[c,s,t]  (materialized in d_ws, 2.2 MB, t-major)
//                out[bc,l,m] = sum_t xf[bc,t,l] * xp[m+t]
// x: [8,2,2048] f32, filt: [1,2,17,17] f32, out: [8,2,2048,2048] f32 (268 MB)
// HBM-write-bound: floor ~ 268MB / ~6.3 TB/s ~ 43 us for the out kernel.
//
// v3: out kernel has NO LDS at all. x (128 KB) and xf (2.2 MB) are L2-resident;
//     staging them in LDS (v1/v2) was pure overhead (barriers + bank conflicts).
//     - tile = 4 rows x full 2048 cols per block -> each block writes one
//       fully CONTIGUOUS 32 KB region (rows are contiguous in memory)
//     - each thread: 2 m-groups of 4 (m=4*tid, 4*tid+1024), 4 l-rows
//       -> every store instruction = 64 lanes x 16 B @ 16 B stride = 1 KB contiguous
//     - w-windows: 5 guarded global_load_dwordx4 per group (pad=8 => chunks are
//       never partial: fully in-range or fully zero)
//     - f-fragment: one dwordx4 per t, same address across all lanes (L1 broadcast)
//     Accumulation order over t unchanged -> bit-identical output.

#define LN   2048
#define S    17
#define PADW 8
#define NBC  16

typedef float f32x4 __attribute__((ext_vector_type(4)));

// ---------------- kernel 1: xf[bc][t][l] = sum_s xp[bc][l+s] * F[c][s][t] -------------
__global__ __launch_bounds__(256) void xf_kernel(
    const float* __restrict__ x,
    const float* __restrict__ filt,
    float* __restrict__ xf)   // [NBC][S][LN]
{
    const int bc = blockIdx.y;
    const int c  = bc & 1;
    const int l  = blockIdx.x * 256 + threadIdx.x;

    __shared__ float sF[S][S];
    for (int i = threadIdx.x; i < S * S; i += 256)
        sF[i / S][i % S] = filt[c * S * S + i];
    __syncthreads();

    const float* __restrict__ xrow = x + (size_t)bc * LN;

    float w[S];
#pragma unroll
    for (int s = 0; s < S; s++) {
        int j = l + s - PADW;
        w[s] = (j >= 0 && j < LN) ? xrow[j] : 0.0f;
    }

    float acc[S];
#pragma unroll
    for (int t = 0; t < S; t++) acc[t] = 0.0f;
#pragma unroll
    for (int s = 0; s < S; s++) {
        const float ws = w[s];
#pragma unroll
        for (int t = 0; t < S; t++)
            acc[t] += ws * sF[s][t];
    }

    float* __restrict__ xfrow = xf + (size_t)bc * S * LN + l;
#pragma unroll
    for (int t = 0; t < S; t++)
        xfrow[(size_t)t * LN] = acc[t];
}

// ---------------- kernel 2: out tile 4(l) x 2048(m), no LDS, store-bound ----------------
__global__ __launch_bounds__(256) void filter_qf_kernel(
    const float* __restrict__ x,
    const float* __restrict__ xf,   // [NBC][S][LN]
    float* __restrict__ out)
{
    const int bc = blockIdx.z;
    const int l0 = blockIdx.y * 4;
    const int tid = threadIdx.x;

    const float* __restrict__ xrow = x + (size_t)bc * LN;
    const float* __restrict__ xfb  = xf + (size_t)bc * S * LN + l0;

    // two m-groups per thread: m1 = 4*tid, m2 = 4*tid + 1024
    const int m1 = 4 * tid;
    const int m2 = m1 + 1024;

    // w-windows: w[i] = xp[m + i - 8], i = 0..19 (5 aligned 4-dword chunks each).
    // Chunk dword offset o = m - 8 + 4k is always a multiple of 4, and the valid
    // region [0, 2048) has multiple-of-4 boundaries -> chunks are never partial.
    float w1[20], w2[20];
#pragma unroll
    for (int k = 0; k < 5; k++) {
        const int o1 = m1 - PADW + 4 * k;
        const int o2 = m2 - PADW + 4 * k;
        f32x4 v1, v2;
        if (o1 >= 0 && o1 < LN) v1 = *reinterpret_cast<const f32x4*>(xrow + o1);
        else                    v1 = f32x4{0.0f, 0.0f, 0.0f, 0.0f};
        if (o2 >= 0 && o2 < LN) v2 = *reinterpret_cast<const f32x4*>(xrow + o2);
        else                    v2 = f32x4{0.0f, 0.0f, 0.0f, 0.0f};
        *reinterpret_cast<f32x4*>(&w1[4 * k]) = v1;
        *reinterpret_cast<f32x4*>(&w2[4 * k]) = v2;
    }

    float acc1[4][4] = {};
    float acc2[4][4] = {};
#pragma unroll
    for (int t = 0; t < S; t++) {
        // same address across all 64 lanes -> single L1 transaction, broadcast
        const f32x4 f = *reinterpret_cast<const f32x4*>(xfb + (size_t)t * LN);
#pragma unroll
        for (int j = 0; j < 4; j++) {
            const float b1 = w1[t + j];
            const float b2 = w2[t + j];
#pragma unroll
            for (int i = 0; i < 4; i++) {
                acc1[i][j] += f[i] * b1;
                acc2[i][j] += f[i] * b2;
            }
        }
    }

    // stores: per instruction, 64 lanes x 16 B at 16 B stride = 1 KB contiguous;
    // whole block covers one contiguous 32 KB region.
    const size_t base = ((size_t)bc * LN + (size_t)l0) * LN;
#pragma unroll
    for (int li = 0; li < 4; li++) {
        f32x4 u1 = { acc1[li][0], acc1[li][1], acc1[li][2], acc1[li][3] };
        f32x4 u2 = { acc2[li][0], acc2[li][1], acc2[li][2], acc2[li][3] };
        float* p = out + base + (size_t)li * LN;
        __builtin_nontemporal_store(u1, reinterpret_cast<f32x4*>(p + m1));
        __builtin_nontemporal_store(u2, reinterpret_cast<f32x4*>(p + m2));
    }
}

// ---------------- fallback (round-1 kernel, 64x64 tile) if ws too small ----------------
#define FTL  64
#define FTM  64

__global__ __launch_bounds__(256) void filter_qf_fallback(
    const float* __restrict__ x,
    const float* __restrict__ filt,
    float* __restrict__ out)
{
    const int bc = blockIdx.z;
    const int c  = bc & 1;
    const int l0 = blockIdx.y * FTL;
    const int m0 = blockIdx.x * FTM;
    const int tid = threadIdx.x;

    __shared__ float sF[S][S];
    __shared__ float sxl[FTL + S - 1];
    __shared__ float sxm[FTM + S - 1];
    __shared__ float sxf[FTL][S + 1];

    const float* __restrict__ xrow = x + (size_t)bc * LN;
    for (int i = tid; i < S * S; i += 256)
        sF[i / S][i % S] = filt[c * S * S + i];
    for (int i = tid; i < FTL + S - 1; i += 256) {
        int j = l0 + i - PADW;
        sxl[i] = (j >= 0 && j < LN) ? xrow[j] : 0.0f;
    }
    for (int i = tid; i < FTM + S - 1; i += 256) {
        int j = m0 + i - PADW;
        sxm[i] = (j >= 0 && j < LN) ? xrow[j] : 0.0f;
    }
    __syncthreads();
    for (int i = tid; i < FTL * S; i += 256) {
        int l = i / S, t = i % S;
        float a = 0.0f;
#pragma unroll
        for (int s = 0; s < S; s++) a += sxl[l + s] * sF[s][t];
        sxf[l][t] = a;
    }
    __syncthreads();
    const int tm = (tid & 15) << 2;
    const int tl = (tid >> 4) << 2;
    float w[4 + S - 1];
#pragma unroll
    for (int i = 0; i < 4 + S - 1; i++) w[i] = sxm[tm + i];
    float acc[4][4] = {{0.f}};
#pragma unroll
    for (int t = 0; t < S; t++) {
        const float f0 = sxf[tl + 0][t], f1 = sxf[tl + 1][t];
        const float f2 = sxf[tl + 2][t], f3 = sxf[tl + 3][t];
#pragma unroll
        for (int j = 0; j < 4; j++) {
            const float b = w[t + j];
            acc[0][j] += f0 * b; acc[1][j] += f1 * b;
            acc[2][j] += f2 * b; acc[3][j] += f3 * b;
        }
    }
    size_t base = (((size_t)bc * LN) + (size_t)(l0 + tl)) * LN + (size_t)(m0 + tm);
#pragma unroll
    for (int li = 0; li < 4; li++) {
        f32x4 v = { acc[li][0], acc[li][1], acc[li][2], acc[li][3] };
        *reinterpret_cast<f32x4*>(out + base + (size_t)li * LN) = v;
    }
}

extern "C" void kernel_launch(void* const* d_in, const int* in_sizes, int n_in,
                              void* d_out, int out_size, void* d_ws, size_t ws_size,
                              hipStream_t stream) {
    const float* x    = (const float*)d_in[0];   // [8,2,2048]
    const float* filt = (const float*)d_in[1];   // [1,2,17,17]
    float* out = (float*)d_out;                  // [8,2,2048,2048]

    const size_t xf_bytes = (size_t)NBC * S * LN * sizeof(float);  // 2.2 MB

    if (ws_size >= xf_bytes) {
        float* xf = (float*)d_ws;
        xf_kernel<<<dim3(LN / 256, NBC), 256, 0, stream>>>(x, filt, xf);
        filter_qf_kernel<<<dim3(1, LN / 4, NBC), 256, 0, stream>>>(x, xf, out);
    } else {
        filter_qf_fallback<<<dim3(LN / FTM, LN / FTL, NBC), 256, 0, stream>>>(x, filt, out);
    }
}